// Round 1
// baseline (255.258 us; speedup 1.0000x reference)
//
#include <hip/hip_runtime.h>
#include <hip/hip_bf16.h>

#define B_ 32
#define L_ 1024
#define D_ 128
#define BI 128
#define BJ 128
#define NT 512
#define PADW 136  // 128 + 8 bf16 pad -> 272B row stride, uniform bank spread

typedef __attribute__((ext_vector_type(8))) short bf8_t;
typedef __attribute__((ext_vector_type(4))) short bf4_t;
typedef __attribute__((ext_vector_type(4))) float f4_t;

__device__ __forceinline__ short f2bf(float f) {
  union { float f; unsigned u; } c; c.f = f;
  unsigned u = c.u + 0x7FFFu + ((c.u >> 16) & 1u);
  return (short)(u >> 16);
}

// Wt[which][d][j] = bf16(W_which[j][d])   (2*128*1024 elems)
__global__ void prep_w_kernel(const float* __restrict__ W0,
                              const float* __restrict__ W1,
                              short* __restrict__ Wt) {
  int idx = blockIdx.x * 256 + threadIdx.x;  // 0 .. 262143
  int which = idx >> 17;
  int rm = idx & 131071;
  int d = rm >> 10;
  int j = rm & 1023;
  const float* W = which ? W1 : W0;
  Wt[idx] = f2bf(W[j * D_ + d]);
}

__global__ __launch_bounds__(NT, 2)
void fused_attnconv(const float* __restrict__ x0,
                    const float* __restrict__ x1,
                    const short* __restrict__ Wt,
                    float* __restrict__ out) {
  __shared__ short a_lds[BI * PADW];
  __shared__ short y_lds[BJ * PADW];
  __shared__ short p_lds[BI * PADW];
  __shared__ float sqx[BI];
  __shared__ float sqy[BJ];

  const int bid = blockIdx.x;
  const int which = bid >> 8;   // 256 blocks per direction
  const int r = bid & 255;
  const int b = r >> 3;
  const int i0 = (r & 7) * BI;

  const float* X = which ? x1 : x0;
  const float* Y = which ? x0 : x1;
  const short* Wp = Wt + which * (D_ * L_);
  float* O = out + (size_t)which * ((size_t)B_ * 2 * L_ * D_)
                 + (size_t)b * (2 * L_ * D_);

  const int tid = threadIdx.x;
  const int lane = tid & 63;
  const int w = tid >> 6;       // wave 0..7, owns rows [w*16, w*16+16)
  const int l15 = lane & 15;
  const int l4 = lane >> 4;

  // ---- stage a-tile (bf16) + write-through channel 0 + sqx ----
  {
    const int row = tid >> 2, qt = tid & 3;
    const float* src = X + ((size_t)b * L_ + i0 + row) * D_ + qt * 32;
    float* dst = O + (size_t)(i0 + row) * D_ + qt * 32;
    short* lr = a_lds + row * PADW + qt * 32;
    float s = 0.f;
#pragma unroll
    for (int q = 0; q < 8; ++q) {
      float4 v = *(const float4*)(src + q * 4);
      *(float4*)(dst + q * 4) = v;
      s += v.x * v.x + v.y * v.y + v.z * v.z + v.w * v.w;
      bf4_t h; h[0] = f2bf(v.x); h[1] = f2bf(v.y); h[2] = f2bf(v.z); h[3] = f2bf(v.w);
      *(bf4_t*)(lr + q * 4) = h;
    }
    s += __shfl_xor(s, 1);
    s += __shfl_xor(s, 2);
    if (qt == 0) sqx[row] = s;
  }

  f4_t zero4 = {0.f, 0.f, 0.f, 0.f};
  f4_t acc2[8];
#pragma unroll
  for (int n = 0; n < 8; ++n) acc2[n] = zero4;

  for (int jt = 0; jt < L_ / BJ; ++jt) {
    const int j0 = jt * BJ;
    __syncthreads();  // a_lds ready (iter 0); y_lds/p_lds consumers done (iter>0)

    // ---- stage y-tile (bf16) + sqy ----
    {
      const int row = tid >> 2, qt = tid & 3;
      const float* src = Y + ((size_t)b * L_ + j0 + row) * D_ + qt * 32;
      short* lr = y_lds + row * PADW + qt * 32;
      float s = 0.f;
#pragma unroll
      for (int q = 0; q < 8; ++q) {
        float4 v = *(const float4*)(src + q * 4);
        s += v.x * v.x + v.y * v.y + v.z * v.z + v.w * v.w;
        bf4_t h; h[0] = f2bf(v.x); h[1] = f2bf(v.y); h[2] = f2bf(v.z); h[3] = f2bf(v.w);
        *(bf4_t*)(lr + q * 4) = h;
      }
      s += __shfl_xor(s, 1);
      s += __shfl_xor(s, 2);
      if (qt == 0) sqy[row] = s;
    }
    __syncthreads();

    // ---- MFMA-1: S = a . y^T  (wave rows w*16..+15, all 128 cols) ----
    f4_t S[8];
#pragma unroll
    for (int n = 0; n < 8; ++n) S[n] = zero4;
#pragma unroll
    for (int kb = 0; kb < 4; ++kb) {
      bf8_t af = *(const bf8_t*)(a_lds + (w * 16 + l15) * PADW + kb * 32 + l4 * 8);
#pragma unroll
      for (int n = 0; n < 8; ++n) {
        bf8_t bfr = *(const bf8_t*)(y_lds + (n * 16 + l15) * PADW + kb * 32 + l4 * 8);
        S[n] = __builtin_amdgcn_mfma_f32_16x16x32_bf16(af, bfr, S[n], 0, 0, 0);
      }
    }

    // ---- elementwise A = 1/(1+dist) -> bf16 p_lds ----
    float sxr[4];
#pragma unroll
    for (int rg = 0; rg < 4; ++rg) sxr[rg] = sqx[w * 16 + l4 * 4 + rg];
#pragma unroll
    for (int n = 0; n < 8; ++n) {
      float sy = sqy[n * 16 + l15];
#pragma unroll
      for (int rg = 0; rg < 4; ++rg) {
        float d2 = fmaxf(sxr[rg] + sy - 2.0f * S[n][rg], 0.0f);
        float Av = 1.0f / (1.0f + sqrtf(d2));
        p_lds[(w * 16 + l4 * 4 + rg) * PADW + n * 16 + l15] = f2bf(Av);
      }
    }
    __syncthreads();

    // ---- MFMA-2: acc2 += P . W  (K = BJ, B-operand from global Wt, L1/L2-hot) ----
#pragma unroll
    for (int kb = 0; kb < 4; ++kb) {
      bf8_t af = *(const bf8_t*)(p_lds + (w * 16 + l15) * PADW + kb * 32 + l4 * 8);
#pragma unroll
      for (int n = 0; n < 8; ++n) {
        bf8_t bfr = *(const bf8_t*)(Wp + (n * 16 + l15) * L_ + j0 + kb * 32 + l4 * 8);
        acc2[n] = __builtin_amdgcn_mfma_f32_16x16x32_bf16(af, bfr, acc2[n], 0, 0, 0);
      }
    }
  }

  // ---- epilogue: channel 1 = acc2 ----
  float* Oc1 = O + L_ * D_;
#pragma unroll
  for (int n = 0; n < 8; ++n) {
#pragma unroll
    for (int rg = 0; rg < 4; ++rg) {
      Oc1[(size_t)(i0 + w * 16 + l4 * 4 + rg) * D_ + n * 16 + l15] = acc2[n][rg];
    }
  }
}

extern "C" void kernel_launch(void* const* d_in, const int* in_sizes, int n_in,
                              void* d_out, int out_size, void* d_ws, size_t ws_size,
                              hipStream_t stream) {
  const float* x0 = (const float*)d_in[0];
  const float* x1 = (const float*)d_in[1];
  const float* W0 = (const float*)d_in[2];
  const float* W1 = (const float*)d_in[3];
  float* out = (float*)d_out;
  short* Wt = (short*)d_ws;  // 2*128*1024 bf16 = 512 KB

  prep_w_kernel<<<1024, 256, 0, stream>>>(W0, W1, Wt);
  fused_attnconv<<<512, NT, 0, stream>>>(x0, x1, Wt, out);
}

// Round 2
// 174.800 us; speedup vs baseline: 1.4603x; 1.4603x over previous
//
#include <hip/hip_runtime.h>

#define B_ 32
#define L_ 1024
#define D_ 128
#define NT 512

typedef __attribute__((ext_vector_type(8))) short bf8_t;
typedef __attribute__((ext_vector_type(4))) short bf4_t;
typedef __attribute__((ext_vector_type(4))) float f4_t;

__device__ __forceinline__ short f2bf(float f) {
  union { float f; unsigned u; } c; c.f = f;
  unsigned u = c.u + 0x7FFFu + ((c.u >> 16) & 1u);
  return (short)(u >> 16);
}

// Wt[which][d][j] = bf16(W_which[j][d])
__global__ void prep_w_kernel(const float* __restrict__ W0,
                              const float* __restrict__ W1,
                              short* __restrict__ Wt) {
  int idx = blockIdx.x * 256 + threadIdx.x;
  int which = idx >> 17;
  int rm = idx & 131071;
  int d = rm >> 10;
  int j = rm & 1023;
  const float* W = which ? W1 : W0;
  Wt[idx] = f2bf(W[j * D_ + d]);
}

__global__ __launch_bounds__(NT, 4)
void fused_attnconv(const float* __restrict__ x0,
                    const float* __restrict__ x1,
                    const short* __restrict__ Wt,
                    float* __restrict__ out) {
  // 256B rows, XOR-swizzled (byte ^= (row&7)<<4) on both write and read.
  __shared__ short a_lds[128 * 128];
  __shared__ short y_lds[128 * 128];  // aliased as P-tile after MFMA-1
  __shared__ float sqx[128];
  __shared__ float sqy[128];

  // XCD-aware decode: low bits = (which,b) so all 8 i-tiles of one Y-panel
  // share an XCD L2 (bid mod 8 == b mod 8 for default round-robin dispatch).
  const int bid = blockIdx.x;
  const int itile = bid >> 6;        // 0..7
  const int which = (bid >> 5) & 1;
  const int b = bid & 31;
  const int i0 = itile * 128;

  const float* X = which ? x1 : x0;
  const float* Y = which ? x0 : x1;
  const short* Wp = Wt + which * (D_ * L_);
  float* O = out + (size_t)which * ((size_t)B_ * 2 * L_ * D_)
                 + (size_t)b * (2 * L_ * D_);

  const int tid = threadIdx.x;
  const int lane = tid & 63;
  const int w = tid >> 6;
  const int l15 = lane & 15;
  const int l4 = lane >> 4;
  const int wr = w & 3;    // wave row-block: 32 rows
  const int wc = w >> 2;   // wave col-block: 64 cols

  char* aB = (char*)a_lds;
  char* yB = (char*)y_lds;

  // ---- stage a-tile (bf16, swizzled) + write-through channel 0 + sqx ----
  {
    const int row = tid >> 2, qt = tid & 3;
    const float* src = X + ((size_t)b * L_ + i0 + row) * D_ + qt * 32;
    float* dst = O + (size_t)(i0 + row) * D_ + qt * 32;
    char* lr = aB + row * 256;
    const int xm = (row & 7) << 4;
    float s = 0.f;
#pragma unroll
    for (int q = 0; q < 8; ++q) {
      float4 v = *(const float4*)(src + q * 4);
      *(float4*)(dst + q * 4) = v;
      s += v.x * v.x + v.y * v.y + v.z * v.z + v.w * v.w;
      bf4_t h; h[0] = f2bf(v.x); h[1] = f2bf(v.y); h[2] = f2bf(v.z); h[3] = f2bf(v.w);
      *(bf4_t*)(lr + ((qt * 64 + q * 8) ^ xm)) = h;
    }
    s += __shfl_xor(s, 1);
    s += __shfl_xor(s, 2);
    if (qt == 0) sqx[row] = s;
  }

  f4_t z4 = {0.f, 0.f, 0.f, 0.f};
  f4_t acc2[2][4];
#pragma unroll
  for (int m = 0; m < 2; ++m)
#pragma unroll
    for (int n = 0; n < 4; ++n) acc2[m][n] = z4;

  for (int jt = 0; jt < 8; ++jt) {
    const int j0 = jt * 128;
    __syncthreads();  // (1) prior MFMA-2 P-reads done; y/P buffer free

    // ---- stage y-tile (bf16, swizzled) + sqy ----
    {
      const int row = tid >> 2, qt = tid & 3;
      const float* src = Y + ((size_t)b * L_ + j0 + row) * D_ + qt * 32;
      char* lr = yB + row * 256;
      const int xm = (row & 7) << 4;
      float s = 0.f;
#pragma unroll
      for (int q = 0; q < 8; ++q) {
        float4 v = *(const float4*)(src + q * 4);
        s += v.x * v.x + v.y * v.y + v.z * v.z + v.w * v.w;
        bf4_t h; h[0] = f2bf(v.x); h[1] = f2bf(v.y); h[2] = f2bf(v.z); h[3] = f2bf(v.w);
        *(bf4_t*)(lr + ((qt * 64 + q * 8) ^ xm)) = h;
      }
      s += __shfl_xor(s, 1);
      s += __shfl_xor(s, 2);
      if (qt == 0) sqy[row] = s;
    }
    __syncthreads();  // (2) a,y,sq ready

    // ---- MFMA-1: S[m][n] = a . y^T  (wave: rows wr*32+m*16, cols wc*64+n*16) ----
    f4_t S[2][4];
#pragma unroll
    for (int m = 0; m < 2; ++m)
#pragma unroll
      for (int n = 0; n < 4; ++n) S[m][n] = z4;
#pragma unroll
    for (int kb = 0; kb < 4; ++kb) {
      const int kc = kb * 64 + l4 * 16;
      const int r0 = wr * 32 + l15;
      bf8_t af0 = *(const bf8_t*)(aB + r0 * 256 + (kc ^ ((r0 & 7) << 4)));
      const int r1 = r0 + 16;
      bf8_t af1 = *(const bf8_t*)(aB + r1 * 256 + (kc ^ ((r1 & 7) << 4)));
#pragma unroll
      for (int n = 0; n < 4; ++n) {
        const int rc = wc * 64 + n * 16 + l15;
        bf8_t yf = *(const bf8_t*)(yB + rc * 256 + (kc ^ ((rc & 7) << 4)));
        S[0][n] = __builtin_amdgcn_mfma_f32_16x16x32_bf16(af0, yf, S[0][n], 0, 0, 0);
        S[1][n] = __builtin_amdgcn_mfma_f32_16x16x32_bf16(af1, yf, S[1][n], 0, 0, 0);
      }
    }
    __syncthreads();  // (3) y-reads done; P-writes may overwrite y buffer

    // ---- elementwise A = 1/(1+dist) -> bf16 P (into y_lds space, swizzled) ----
    float sx[2][4];
#pragma unroll
    for (int m = 0; m < 2; ++m)
#pragma unroll
      for (int rg = 0; rg < 4; ++rg) sx[m][rg] = sqx[wr * 32 + m * 16 + l4 * 4 + rg];
#pragma unroll
    for (int n = 0; n < 4; ++n) {
      const float sy = sqy[wc * 64 + n * 16 + l15];
      const int bc = 2 * (wc * 64 + n * 16 + l15);
#pragma unroll
      for (int m = 0; m < 2; ++m) {
#pragma unroll
        for (int rg = 0; rg < 4; ++rg) {
          float d2 = fmaxf(sx[m][rg] + sy - 2.0f * S[m][n][rg], 0.0f);
          float Av = 1.0f / (1.0f + sqrtf(d2));
          const int row = wr * 32 + m * 16 + l4 * 4 + rg;
          *(short*)(yB + row * 256 + (bc ^ ((row & 7) << 4))) = f2bf(Av);
        }
      }
    }
    __syncthreads();  // (4) P ready

    // ---- MFMA-2: acc2 += P . W  (K=128; B-operand = Wt[d][j] global, L2-hot) ----
#pragma unroll
    for (int kb = 0; kb < 4; ++kb) {
      const int kc = kb * 64 + l4 * 16;
      const int r0 = wr * 32 + l15;
      bf8_t pf0 = *(const bf8_t*)(yB + r0 * 256 + (kc ^ ((r0 & 7) << 4)));
      const int r1 = r0 + 16;
      bf8_t pf1 = *(const bf8_t*)(yB + r1 * 256 + (kc ^ ((r1 & 7) << 4)));
#pragma unroll
      for (int n = 0; n < 4; ++n) {
        bf8_t wf = *(const bf8_t*)(Wp + (wc * 64 + n * 16 + l15) * L_ + j0 + kb * 32 + l4 * 8);
        acc2[0][n] = __builtin_amdgcn_mfma_f32_16x16x32_bf16(pf0, wf, acc2[0][n], 0, 0, 0);
        acc2[1][n] = __builtin_amdgcn_mfma_f32_16x16x32_bf16(pf1, wf, acc2[1][n], 0, 0, 0);
      }
    }
  }

  // ---- epilogue: channel 1 = acc2 ----
  float* Oc1 = O + L_ * D_;
#pragma unroll
  for (int m = 0; m < 2; ++m) {
#pragma unroll
    for (int n = 0; n < 4; ++n) {
#pragma unroll
      for (int rg = 0; rg < 4; ++rg) {
        Oc1[(size_t)(i0 + wr * 32 + m * 16 + l4 * 4 + rg) * D_ + wc * 64 + n * 16 + l15] =
            acc2[m][n][rg];
      }
    }
  }
}

extern "C" void kernel_launch(void* const* d_in, const int* in_sizes, int n_in,
                              void* d_out, int out_size, void* d_ws, size_t ws_size,
                              hipStream_t stream) {
  const float* x0 = (const float*)d_in[0];
  const float* x1 = (const float*)d_in[1];
  const float* W0 = (const float*)d_in[2];
  const float* W1 = (const float*)d_in[3];
  float* out = (float*)d_out;
  short* Wt = (short*)d_ws;  // 2*128*1024 bf16 = 512 KB

  prep_w_kernel<<<1024, 256, 0, stream>>>(W0, W1, Wt);
  fused_attnconv<<<512, NT, 0, stream>>>(x0, x1, Wt, out);
}

// Round 4
// 170.164 us; speedup vs baseline: 1.5001x; 1.0272x over previous
//
#include <hip/hip_runtime.h>

#define B_ 32
#define L_ 1024
#define D_ 128
#define NT 512

typedef __attribute__((ext_vector_type(8))) short bf8_t;
typedef __attribute__((ext_vector_type(4))) float f4_t;

__device__ __forceinline__ unsigned cvtpk(float lo, float hi) {
  unsigned r;
  asm("v_cvt_pk_bf16_f32 %0, %1, %2" : "=v"(r) : "v"(lo), "v"(hi));
  return r;
}

__device__ __forceinline__ void gload16(const void* g, void* l) {
  __builtin_amdgcn_global_load_lds((const __attribute__((address_space(1))) void*)g,
                                   (__attribute__((address_space(3))) void*)l, 16, 0, 0);
}

// One prologue pass: pre-swizzled bf16 X panels + sq + channel-0 copy + W^T(bf16).
__global__ __launch_bounds__(256)
void prep_kernel(const float* __restrict__ x0, const float* __restrict__ x1,
                 const float* __restrict__ W0, const float* __restrict__ W1,
                 short* __restrict__ Xs, float* __restrict__ sq,
                 short* __restrict__ Wt, float* __restrict__ out) {
  int bid = blockIdx.x;
  if (bid < 8192) {
    int t = bid * 256 + threadIdx.x;     // 0 .. 2097151
    int row_id = t >> 5;                 // (which,b,row)
    int qp = t & 31;
    int which = row_id >> 15;
    int b = (row_id >> 10) & 31;
    int row = row_id & 1023;
    const float* x = which ? x1 : x0;
    float4 v = *(const float4*)(x + ((size_t)b * L_ + row) * D_ + qp * 4);
    // channel-0 write-through
    float* o = out + (size_t)which * (B_ * 2 * L_ * D_) + (size_t)b * (2 * L_ * D_)
             + (size_t)row * D_ + qp * 4;
    *(float4*)o = v;
    // pre-swizzled bf16 (XOR swizzle baked into global layout)
    unsigned w0 = cvtpk(v.x, v.y), w1 = cvtpk(v.z, v.w);
    char* xb = (char*)Xs + (size_t)row_id * 256 + ((qp * 8) ^ ((row & 7) << 4));
    *(uint2*)xb = make_uint2(w0, w1);
    // sum of squares (fp32)
    float s = v.x * v.x + v.y * v.y + v.z * v.z + v.w * v.w;
    s += __shfl_xor(s, 1); s += __shfl_xor(s, 2); s += __shfl_xor(s, 4);
    s += __shfl_xor(s, 8); s += __shfl_xor(s, 16);
    if (qp == 0) sq[row_id] = s;
  } else {
    int idx = (bid - 8192) * 256 + threadIdx.x;  // 0..262143
    int which = idx >> 17;
    int rm = idx & 131071;
    int d = rm >> 10;
    int j = rm & 1023;
    const float* W = which ? W1 : W0;
    float wv = W[j * D_ + d];
    Wt[idx] = (short)(cvtpk(wv, wv) & 0xffffu);
  }
}

__global__ __launch_bounds__(NT, 6)
void fused_attnconv(const short* __restrict__ Xs, const float* __restrict__ sq,
                    const short* __restrict__ Wt, float* __restrict__ out) {
  __shared__ char smem[49152];  // [0,16K) a-tile (64 rows), [16K,48K) y-tile/P (aliased)
  char* aB = smem;
  char* yB = smem + 16384;

  // XCD-grouped decode: XCD x gets 16 consecutive i-blocks of one (which,b) panel.
  const int bid = blockIdx.x;
  const int x = bid & 7, g = bid >> 3;
  const int p = x + 8 * (g >> 4);   // panel id = which*32+b, 0..63
  const int it = g & 15;            // i-tile 0..15
  const int which = p >> 5, b = p & 31;
  const int i0 = it * 64;
  const int po = (which ^ 1) * 32 + b;  // OPPOSITE tensor's panel: y-side

  const char* apanel = (const char*)Xs + (size_t)p * (L_ * 256);
  const char* ypanel = (const char*)Xs + (size_t)po * (L_ * 256);
  const char* aSrc = apanel + (size_t)i0 * 256;
  const float* sqx_p = sq + p * L_;
  const float* sqy_p = sq + po * L_;
  const short* Wp = Wt + which * (D_ * L_);
  float* Oc1 = out + (size_t)which * (B_ * 2 * L_ * D_) + (size_t)b * (2 * L_ * D_) + (L_ * D_);

  const int tid = threadIdx.x;
  const int lane = tid & 63;
  const int w = tid >> 6;
  const int l15 = lane & 15;
  const int q = lane >> 4;
  const int wr = w & 3;          // i-block within tile: 16 rows
  const int wc = w >> 2;         // j/d-block: 64 cols
  const int I0 = wr * 16;
  const int J0 = wc * 64;
  const int swz = (l15 & 7) << 4;

  const float sxv = sqx_p[i0 + I0 + l15];

  // stage a-tile (16 KB) + y-tile jt=0 (32 KB) via global_load_lds x16
  {
    const char* gs = aSrc + w * 2048 + lane * 16;
    char* ls = aB + w * 2048 + lane * 16;
    gload16(gs, ls);
    gload16(gs + 1024, ls + 1024);
    const char* gy = ypanel + w * 4096 + lane * 16;
    char* ly = yB + w * 4096 + lane * 16;
    gload16(gy, ly);
    gload16(gy + 1024, ly + 1024);
    gload16(gy + 2048, ly + 2048);
    gload16(gy + 3072, ly + 3072);
  }
  f4_t z4 = {0.f, 0.f, 0.f, 0.f};
  f4_t acc[4] = {z4, z4, z4, z4};
  __syncthreads();  // staged (vmcnt(0) drained before barrier)

  for (int jt = 0; jt < 8; ++jt) {
    // sqy for this wave's j-columns
    f4_t sy[4];
#pragma unroll
    for (int n = 0; n < 4; ++n)
      sy[n] = *(const f4_t*)(sqy_p + jt * 128 + J0 + n * 16 + q * 4);

    // MFMA-1 (swapped): ST[n] = y . a^T  -> lane holds i=l15 fixed, j=q*4+reg
    f4_t ST[4] = {z4, z4, z4, z4};
#pragma unroll
    for (int kb = 0; kb < 4; ++kb) {
      const int kc = (kb * 64 + q * 16) ^ swz;
      bf8_t af = *(const bf8_t*)(aB + (I0 + l15) * 256 + kc);
#pragma unroll
      for (int n = 0; n < 4; ++n) {
        bf8_t yf = *(const bf8_t*)(yB + (J0 + n * 16 + l15) * 256 + kc);
        ST[n] = __builtin_amdgcn_mfma_f32_16x16x32_bf16(yf, af, ST[n], 0, 0, 0);
      }
    }
    __syncthreads();  // y-reads done; P may overwrite buffer

    // elementwise A = 1/(1+sqrt(d2)), packed b64 P-writes (row=i, 4 consecutive j)
#pragma unroll
    for (int n = 0; n < 4; ++n) {
      float A0 = __builtin_amdgcn_rcpf(1.0f + __builtin_amdgcn_sqrtf(fmaxf(__builtin_fmaf(-2.f, ST[n][0], sxv + sy[n][0]), 0.f)));
      float A1 = __builtin_amdgcn_rcpf(1.0f + __builtin_amdgcn_sqrtf(fmaxf(__builtin_fmaf(-2.f, ST[n][1], sxv + sy[n][1]), 0.f)));
      float A2 = __builtin_amdgcn_rcpf(1.0f + __builtin_amdgcn_sqrtf(fmaxf(__builtin_fmaf(-2.f, ST[n][2], sxv + sy[n][2]), 0.f)));
      float A3 = __builtin_amdgcn_rcpf(1.0f + __builtin_amdgcn_sqrtf(fmaxf(__builtin_fmaf(-2.f, ST[n][3], sxv + sy[n][3]), 0.f)));
      unsigned w0 = cvtpk(A0, A1), w1 = cvtpk(A2, A3);
      char* pw = yB + (I0 + l15) * 256 + ((J0 * 2 + n * 32 + q * 8) ^ swz);
      *(uint2*)pw = make_uint2(w0, w1);
    }
    __syncthreads();  // P ready

    // MFMA-2: acc[n] += P . W   (A=P rows i, K=128 j; B=Wt[d][j] global, L2-hot)
#pragma unroll
    for (int kb = 0; kb < 4; ++kb) {
      const int kc = (kb * 64 + q * 16) ^ swz;
      bf8_t pf = *(const bf8_t*)(yB + (I0 + l15) * 256 + kc);
#pragma unroll
      for (int n = 0; n < 4; ++n) {
        bf8_t wf = *(const bf8_t*)(Wp + (J0 + n * 16 + l15) * L_ + jt * 128 + kb * 32 + q * 8);
        acc[n] = __builtin_amdgcn_mfma_f32_16x16x32_bf16(pf, wf, acc[n], 0, 0, 0);
      }
    }

    if (jt < 7) {
      __syncthreads();  // P-reads done; y buffer free
      const char* gy = ypanel + (jt + 1) * 32768 + w * 4096 + lane * 16;
      char* ly = yB + w * 4096 + lane * 16;
      gload16(gy, ly);
      gload16(gy + 1024, ly + 1024);
      gload16(gy + 2048, ly + 2048);
      gload16(gy + 3072, ly + 3072);
      __syncthreads();  // staged
    }
  }

  // epilogue: channel 1
#pragma unroll
  for (int n = 0; n < 4; ++n) {
    const int d = J0 + n * 16 + l15;
#pragma unroll
    for (int r = 0; r < 4; ++r) {
      Oc1[(size_t)(i0 + I0 + q * 4 + r) * D_ + d] = acc[n][r];
    }
  }
}

extern "C" void kernel_launch(void* const* d_in, const int* in_sizes, int n_in,
                              void* d_out, int out_size, void* d_ws, size_t ws_size,
                              hipStream_t stream) {
  const float* x0 = (const float*)d_in[0];
  const float* x1 = (const float*)d_in[1];
  const float* W0 = (const float*)d_in[2];
  const float* W1 = (const float*)d_in[3];
  float* out = (float*)d_out;

  char* ws = (char*)d_ws;
  short* Wt = (short*)ws;                       // 512 KB
  short* Xs = (short*)(ws + 524288);            // 16.78 MB, pre-swizzled bf16
  float* sq = (float*)(ws + 524288 + 16777216); // 256 KB

  prep_kernel<<<9216, 256, 0, stream>>>(x0, x1, W0, W1, Xs, sq, Wt, out);
  fused_attnconv<<<1024, NT, 0, stream>>>(Xs, sq, Wt, out);
}

// Round 5
// 167.678 us; speedup vs baseline: 1.5223x; 1.0148x over previous
//
#include <hip/hip_runtime.h>

#define B_ 32
#define L_ 1024
#define D_ 128
#define NT 512

typedef __attribute__((ext_vector_type(8))) short bf8_t;
typedef __attribute__((ext_vector_type(4))) float f4_t;

__device__ __forceinline__ unsigned cvtpk(float lo, float hi) {
  unsigned r;
  asm("v_cvt_pk_bf16_f32 %0, %1, %2" : "=v"(r) : "v"(lo), "v"(hi));
  return r;
}

__device__ __forceinline__ void gload16(const void* g, void* l) {
  __builtin_amdgcn_global_load_lds((const __attribute__((address_space(1))) void*)g,
                                   (__attribute__((address_space(3))) void*)l, 16, 0, 0);
}

// One prologue pass: pre-swizzled bf16 X panels + sq + channel-0 copy + W^T(bf16).
__global__ __launch_bounds__(256)
void prep_kernel(const float* __restrict__ x0, const float* __restrict__ x1,
                 const float* __restrict__ W0, const float* __restrict__ W1,
                 short* __restrict__ Xs, float* __restrict__ sq,
                 short* __restrict__ Wt, float* __restrict__ out) {
  int bid = blockIdx.x;
  if (bid < 8192) {
    int t = bid * 256 + threadIdx.x;     // 0 .. 2097151
    int row_id = t >> 5;                 // (which,b,row)
    int qp = t & 31;
    int which = row_id >> 15;
    int b = (row_id >> 10) & 31;
    int row = row_id & 1023;
    const float* x = which ? x1 : x0;
    float4 v = *(const float4*)(x + ((size_t)b * L_ + row) * D_ + qp * 4);
    float* o = out + (size_t)which * (B_ * 2 * L_ * D_) + (size_t)b * (2 * L_ * D_)
             + (size_t)row * D_ + qp * 4;
    *(float4*)o = v;
    unsigned w0 = cvtpk(v.x, v.y), w1 = cvtpk(v.z, v.w);
    char* xb = (char*)Xs + (size_t)row_id * 256 + ((qp * 8) ^ ((row & 7) << 4));
    *(uint2*)xb = make_uint2(w0, w1);
    float s = v.x * v.x + v.y * v.y + v.z * v.z + v.w * v.w;
    s += __shfl_xor(s, 1); s += __shfl_xor(s, 2); s += __shfl_xor(s, 4);
    s += __shfl_xor(s, 8); s += __shfl_xor(s, 16);
    if (qp == 0) sq[row_id] = s;
  } else {
    int idx = (bid - 8192) * 256 + threadIdx.x;  // 0..262143
    int which = idx >> 17;
    int rm = idx & 131071;
    int d = rm >> 10;
    int j = rm & 1023;
    const float* W = which ? W1 : W0;
    float wv = W[j * D_ + d];
    Wt[idx] = (short)(cvtpk(wv, wv) & 0xffffu);
  }
}

__global__ __launch_bounds__(NT, 4)
void fused_attnconv(const short* __restrict__ Xs, const float* __restrict__ sq,
                    const short* __restrict__ Wt, float* __restrict__ out) {
  // [0,16K) ybuf0  [16K,32K) ybuf1  [32K,40K) P (64 rows x 128B, XOR-swizzled)
  __shared__ char smem[40960];
  char* Pb = smem + 32768;

  const int bid = blockIdx.x;
  const int x = bid & 7, g = bid >> 3;
  const int p = x + 8 * (g >> 4);       // panel id = which*32+b
  const int it = g & 15;                // i-tile (64 rows)
  const int which = p >> 5, b = p & 31;
  const int i0 = it * 64;
  const int po = (which ^ 1) * 32 + b;  // opposite tensor: y-side

  const char* apanel = (const char*)Xs + (size_t)p * (L_ * 256);
  const char* ypanel = (const char*)Xs + (size_t)po * (L_ * 256);
  const float* sqx_p = sq + p * L_;
  const float* sqy_p = sq + po * L_;
  const short* Wp = Wt + which * (D_ * L_);
  float* Oc1 = out + (size_t)which * (B_ * 2 * L_ * D_) + (size_t)b * (2 * L_ * D_) + (L_ * D_);

  const int tid = threadIdx.x;
  const int lane = tid & 63;
  const int w = tid >> 6;
  const int l15 = lane & 15;
  const int q = lane >> 4;
  const int wr = w & 3;           // i-strip: rows I0..I0+15
  const int wc = w >> 2;          // j-half of the 64-wide tile: J0..J0+31
  const int I0 = wr * 16;
  const int J0 = wc * 32;
  const int swz = (l15 & 7) << 4;

  // a-fragments in registers (global Xs is pre-swizzled -> apply same XOR)
  bf8_t afr[4];
#pragma unroll
  for (int kb = 0; kb < 4; ++kb)
    afr[kb] = *(const bf8_t*)(apanel + (size_t)(i0 + I0 + l15) * 256 + ((kb * 64 + q * 16) ^ swz));
  const float sxv = sqx_p[i0 + I0 + l15];

  // stage y-tile 0 (16 KB)
  gload16(ypanel + tid * 16, smem + tid * 16);
  gload16(ypanel + 8192 + tid * 16, smem + 8192 + tid * 16);

  f4_t z4 = {0.f, 0.f, 0.f, 0.f};
  f4_t acc[8];
#pragma unroll
  for (int m = 0; m < 8; ++m) acc[m] = z4;

  __syncthreads();  // compiler drains vmcnt(0) before barrier

  for (int jt = 0; jt < 16; ++jt) {
    char* yB = smem + (jt & 1) * 16384;
    // prefetch next y-tile into the other buffer; lands during this iter's compute
    if (jt < 15) {
      char* yN = smem + ((jt + 1) & 1) * 16384;
      const char* gy = ypanel + (jt + 1) * 16384 + tid * 16;
      gload16(gy, yN + tid * 16);
      gload16(gy + 8192, yN + 8192 + tid * 16);
    }
    f4_t sy0 = *(const f4_t*)(sqy_p + jt * 64 + J0 + q * 4);
    f4_t sy1 = *(const f4_t*)(sqy_p + jt * 64 + J0 + 16 + q * 4);

    // MFMA-1 (swapped): ST[n] = y . a^T ; lane holds i=l15, j=J0+n*16+q*4+r
    f4_t ST0 = z4, ST1 = z4;
#pragma unroll
    for (int kb = 0; kb < 4; ++kb) {
      const int kc = (kb * 64 + q * 16) ^ swz;
      bf8_t yf0 = *(const bf8_t*)(yB + (J0 + l15) * 256 + kc);
      bf8_t yf1 = *(const bf8_t*)(yB + (J0 + 16 + l15) * 256 + kc);
      ST0 = __builtin_amdgcn_mfma_f32_16x16x32_bf16(yf0, afr[kb], ST0, 0, 0, 0);
      ST1 = __builtin_amdgcn_mfma_f32_16x16x32_bf16(yf1, afr[kb], ST1, 0, 0, 0);
    }

    // elementwise A = 1/(1+dist) -> wave-private P columns [J0, J0+32)
    {
      float A0 = __builtin_amdgcn_rcpf(1.0f + __builtin_amdgcn_sqrtf(fmaxf(__builtin_fmaf(-2.f, ST0[0], sxv + sy0[0]), 0.f)));
      float A1 = __builtin_amdgcn_rcpf(1.0f + __builtin_amdgcn_sqrtf(fmaxf(__builtin_fmaf(-2.f, ST0[1], sxv + sy0[1]), 0.f)));
      float A2 = __builtin_amdgcn_rcpf(1.0f + __builtin_amdgcn_sqrtf(fmaxf(__builtin_fmaf(-2.f, ST0[2], sxv + sy0[2]), 0.f)));
      float A3 = __builtin_amdgcn_rcpf(1.0f + __builtin_amdgcn_sqrtf(fmaxf(__builtin_fmaf(-2.f, ST0[3], sxv + sy0[3]), 0.f)));
      *(uint2*)(Pb + (I0 + l15) * 128 + ((J0 * 2 + q * 8) ^ swz)) =
          make_uint2(cvtpk(A0, A1), cvtpk(A2, A3));
      float B0 = __builtin_amdgcn_rcpf(1.0f + __builtin_amdgcn_sqrtf(fmaxf(__builtin_fmaf(-2.f, ST1[0], sxv + sy1[0]), 0.f)));
      float B1 = __builtin_amdgcn_rcpf(1.0f + __builtin_amdgcn_sqrtf(fmaxf(__builtin_fmaf(-2.f, ST1[1], sxv + sy1[1]), 0.f)));
      float B2 = __builtin_amdgcn_rcpf(1.0f + __builtin_amdgcn_sqrtf(fmaxf(__builtin_fmaf(-2.f, ST1[2], sxv + sy1[2]), 0.f)));
      float B3 = __builtin_amdgcn_rcpf(1.0f + __builtin_amdgcn_sqrtf(fmaxf(__builtin_fmaf(-2.f, ST1[3], sxv + sy1[3]), 0.f)));
      *(uint2*)(Pb + (I0 + l15) * 128 + ((J0 * 2 + 32 + q * 8) ^ swz)) =
          make_uint2(cvtpk(B0, B1), cvtpk(B2, B3));
    }

    // MFMA-2 (K-split): acc[m] += P[:, J0..J0+32) . W[J0..J0+32, :]
    // pf is exactly the columns THIS wave just wrote -> in-wave lgkm order only.
    bf8_t pf = *(const bf8_t*)(Pb + (I0 + l15) * 128 + ((J0 * 2 + q * 16) ^ swz));
#pragma unroll
    for (int m = 0; m < 8; ++m) {
      bf8_t wf = *(const bf8_t*)(Wp + (m * 16 + l15) * L_ + jt * 64 + J0 + q * 8);
      acc[m] = __builtin_amdgcn_mfma_f32_16x16x32_bf16(pf, wf, acc[m], 0, 0, 0);
    }

    __syncthreads();  // single barrier: next y staged + all waves done with yB
  }

  // epilogue: pair-reduce partial accs across wc partners, then store
  f4_t* ex = (f4_t*)smem;
  const int partner = w ^ 4;
#pragma unroll
  for (int k = 0; k < 4; ++k)
    ex[w * 256 + k * 64 + lane] = acc[(1 - wc) * 4 + k];  // send partner's d-range
  __syncthreads();
#pragma unroll
  for (int k = 0; k < 4; ++k) {
    const int m = wc * 4 + k;
    f4_t other = ex[partner * 256 + k * 64 + lane];
    const int d = m * 16 + l15;
#pragma unroll
    for (int r = 0; r < 4; ++r)
      Oc1[(size_t)(i0 + I0 + q * 4 + r) * D_ + d] = acc[m][r] + other[r];
  }
}

extern "C" void kernel_launch(void* const* d_in, const int* in_sizes, int n_in,
                              void* d_out, int out_size, void* d_ws, size_t ws_size,
                              hipStream_t stream) {
  const float* x0 = (const float*)d_in[0];
  const float* x1 = (const float*)d_in[1];
  const float* W0 = (const float*)d_in[2];
  const float* W1 = (const float*)d_in[3];
  float* out = (float*)d_out;

  char* ws = (char*)d_ws;
  short* Wt = (short*)ws;                       // 512 KB
  short* Xs = (short*)(ws + 524288);            // 16.78 MB, pre-swizzled bf16
  float* sq = (float*)(ws + 524288 + 16777216); // 256 KB

  prep_kernel<<<9216, 256, 0, stream>>>(x0, x1, W0, W1, Xs, sq, Wt, out);
  fused_attnconv<<<1024, NT, 0, stream>>>(Xs, sq, Wt, out);
}

// Round 6
// 116.847 us; speedup vs baseline: 2.1846x; 1.4350x over previous
//
#include <hip/hip_runtime.h>

#define B_ 32
#define L_ 1024
#define D_ 128
#define NT 512

typedef __attribute__((ext_vector_type(8))) short bf8_t;
typedef __attribute__((ext_vector_type(4))) float f4_t;

__device__ __forceinline__ unsigned cvtpk(float lo, float hi) {
  unsigned r;
  asm("v_cvt_pk_bf16_f32 %0, %1, %2" : "=v"(r) : "v"(lo), "v"(hi));
  return r;
}

__device__ __forceinline__ void gload16(const void* g, void* l) {
  __builtin_amdgcn_global_load_lds((const __attribute__((address_space(1))) void*)g,
                                   (__attribute__((address_space(3))) void*)l, 16, 0, 0);
}

// Prologue: pre-swizzled bf16 X panels + sq + channel-0 copy + W in
// fragment-coalesced layout Wc[which][j/32][d][j%32] (bf16).
__global__ __launch_bounds__(256)
void prep_kernel(const float* __restrict__ x0, const float* __restrict__ x1,
                 const float* __restrict__ W0, const float* __restrict__ W1,
                 short* __restrict__ Xs, float* __restrict__ sq,
                 short* __restrict__ Wt, float* __restrict__ out) {
  int bid = blockIdx.x;
  if (bid < 8192) {
    int t = bid * 256 + threadIdx.x;     // 0 .. 2097151
    int row_id = t >> 5;                 // (which,b,row)
    int qp = t & 31;
    int which = row_id >> 15;
    int b = (row_id >> 10) & 31;
    int row = row_id & 1023;
    const float* x = which ? x1 : x0;
    float4 v = *(const float4*)(x + ((size_t)b * L_ + row) * D_ + qp * 4);
    float* o = out + (size_t)which * (B_ * 2 * L_ * D_) + (size_t)b * (2 * L_ * D_)
             + (size_t)row * D_ + qp * 4;
    *(float4*)o = v;
    unsigned w0 = cvtpk(v.x, v.y), w1 = cvtpk(v.z, v.w);
    char* xb = (char*)Xs + (size_t)row_id * 256 + ((qp * 8) ^ ((row & 7) << 4));
    *(uint2*)xb = make_uint2(w0, w1);
    float s = v.x * v.x + v.y * v.y + v.z * v.z + v.w * v.w;
    s += __shfl_xor(s, 1); s += __shfl_xor(s, 2); s += __shfl_xor(s, 4);
    s += __shfl_xor(s, 8); s += __shfl_xor(s, 16);
    if (qp == 0) sq[row_id] = s;
  } else {
    int idx = (bid - 8192) * 256 + threadIdx.x;  // 0..262143
    int which = idx >> 17;
    int rm = idx & 131071;
    int j32 = rm >> 12;
    int d = (rm >> 5) & 127;
    int jj = rm & 31;
    const float* W = which ? W1 : W0;
    float wv = W[(j32 * 32 + jj) * D_ + d];
    Wt[idx] = (short)(cvtpk(wv, wv) & 0xffffu);
  }
}

__global__ __launch_bounds__(NT, 4)
void fused_attnconv(const short* __restrict__ Xs, const float* __restrict__ sq,
                    const short* __restrict__ Wt, float* __restrict__ out) {
  // [0,16K) ybuf0  [16K,32K) ybuf1  [32K,40K) P (64 rows x 128B, XOR-swizzled)
  __shared__ char smem[40960];
  char* Pb = smem + 32768;

  const int bid = blockIdx.x;
  const int x = bid & 7, g = bid >> 3;
  const int p = x + 8 * (g >> 4);       // panel id = which*32+b
  const int it = g & 15;                // i-tile (64 rows)
  const int which = p >> 5, b = p & 31;
  const int i0 = it * 64;
  const int po = (which ^ 1) * 32 + b;  // opposite tensor: y-side

  const char* apanel = (const char*)Xs + (size_t)p * (L_ * 256);
  const char* ypanel = (const char*)Xs + (size_t)po * (L_ * 256);
  const float* sqx_p = sq + p * L_;
  const float* sqy_p = sq + po * L_;
  float* Oc1 = out + (size_t)which * (B_ * 2 * L_ * D_) + (size_t)b * (2 * L_ * D_) + (L_ * D_);

  const int tid = threadIdx.x;
  const int lane = tid & 63;
  const int w = tid >> 6;
  const int l15 = lane & 15;
  const int q = lane >> 4;
  const int wr = w & 3;           // i-strip: rows I0..I0+15
  const int wc = w >> 2;          // j-half of the 64-wide tile: J0..J0+31
  const int I0 = wr * 16;
  const int J0 = wc * 32;
  const int swz = (l15 & 7) << 4;

  // a-fragments in registers (global Xs is pre-swizzled -> apply same XOR)
  bf8_t afr[4];
#pragma unroll
  for (int kb = 0; kb < 4; ++kb)
    afr[kb] = *(const bf8_t*)(apanel + (size_t)(i0 + I0 + l15) * 256 + ((kb * 64 + q * 16) ^ swz));
  const float sxv = sqx_p[i0 + I0 + l15];

  // stage y-tile 0 (16 KB)
  gload16(ypanel + tid * 16, smem + tid * 16);
  gload16(ypanel + 8192 + tid * 16, smem + 8192 + tid * 16);

  f4_t z4 = {0.f, 0.f, 0.f, 0.f};
  f4_t acc[8];
#pragma unroll
  for (int m = 0; m < 8; ++m) acc[m] = z4;

  __syncthreads();  // compiler drains vmcnt(0) before barrier

  for (int jt = 0; jt < 16; ++jt) {
    char* yB = smem + (jt & 1) * 16384;

    // 1) W fragments for this iter -> regs. Coalesced: 64 lanes read one
    //    contiguous 1KB segment per load (lane byte = l15*64 + q*16).
    const short* Wb = Wt + ((size_t)(which * 32 + jt * 2 + wc) * 128) * 32;
    bf8_t wreg[8];
#pragma unroll
    for (int m = 0; m < 8; ++m)
      wreg[m] = *(const bf8_t*)(Wb + (m * 16 + l15) * 32 + q * 8);

    // 2) prefetch next y-tile (issued after W loads: vmcnt FIFO keeps W usable)
    if (jt < 15) {
      char* yN = smem + ((jt + 1) & 1) * 16384;
      const char* gy = ypanel + (jt + 1) * 16384 + tid * 16;
      gload16(gy, yN + tid * 16);
      gload16(gy + 8192, yN + 8192 + tid * 16);
    }
    f4_t sy0 = *(const f4_t*)(sqy_p + jt * 64 + J0 + q * 4);
    f4_t sy1 = *(const f4_t*)(sqy_p + jt * 64 + J0 + 16 + q * 4);

    // 3) MFMA-1 (swapped): ST = y . a^T ; lane holds i=l15, j=J0+n*16+q*4+r
    f4_t ST0 = z4, ST1 = z4;
#pragma unroll
    for (int kb = 0; kb < 4; ++kb) {
      const int kc = (kb * 64 + q * 16) ^ swz;
      bf8_t yf0 = *(const bf8_t*)(yB + (J0 + l15) * 256 + kc);
      bf8_t yf1 = *(const bf8_t*)(yB + (J0 + 16 + l15) * 256 + kc);
      ST0 = __builtin_amdgcn_mfma_f32_16x16x32_bf16(yf0, afr[kb], ST0, 0, 0, 0);
      ST1 = __builtin_amdgcn_mfma_f32_16x16x32_bf16(yf1, afr[kb], ST1, 0, 0, 0);
    }

    // 4) elementwise A = 1/(1+dist) -> wave-private P columns [J0, J0+32)
    {
      float A0 = __builtin_amdgcn_rcpf(1.0f + __builtin_amdgcn_sqrtf(fmaxf(__builtin_fmaf(-2.f, ST0[0], sxv + sy0[0]), 0.f)));
      float A1 = __builtin_amdgcn_rcpf(1.0f + __builtin_amdgcn_sqrtf(fmaxf(__builtin_fmaf(-2.f, ST0[1], sxv + sy0[1]), 0.f)));
      float A2 = __builtin_amdgcn_rcpf(1.0f + __builtin_amdgcn_sqrtf(fmaxf(__builtin_fmaf(-2.f, ST0[2], sxv + sy0[2]), 0.f)));
      float A3 = __builtin_amdgcn_rcpf(1.0f + __builtin_amdgcn_sqrtf(fmaxf(__builtin_fmaf(-2.f, ST0[3], sxv + sy0[3]), 0.f)));
      *(uint2*)(Pb + (I0 + l15) * 128 + ((J0 * 2 + q * 8) ^ swz)) =
          make_uint2(cvtpk(A0, A1), cvtpk(A2, A3));
      float B0 = __builtin_amdgcn_rcpf(1.0f + __builtin_amdgcn_sqrtf(fmaxf(__builtin_fmaf(-2.f, ST1[0], sxv + sy1[0]), 0.f)));
      float B1 = __builtin_amdgcn_rcpf(1.0f + __builtin_amdgcn_sqrtf(fmaxf(__builtin_fmaf(-2.f, ST1[1], sxv + sy1[1]), 0.f)));
      float B2 = __builtin_amdgcn_rcpf(1.0f + __builtin_amdgcn_sqrtf(fmaxf(__builtin_fmaf(-2.f, ST1[2], sxv + sy1[2]), 0.f)));
      float B3 = __builtin_amdgcn_rcpf(1.0f + __builtin_amdgcn_sqrtf(fmaxf(__builtin_fmaf(-2.f, ST1[3], sxv + sy1[3]), 0.f)));
      *(uint2*)(Pb + (I0 + l15) * 128 + ((J0 * 2 + 32 + q * 8) ^ swz)) =
          make_uint2(cvtpk(B0, B1), cvtpk(B2, B3));
    }

    // 5) MFMA-2 (K-split): acc[m] += P[:, J0..J0+32) . W[J0..J0+32, :]
    bf8_t pf = *(const bf8_t*)(Pb + (I0 + l15) * 128 + ((J0 * 2 + q * 16) ^ swz));
#pragma unroll
    for (int m = 0; m < 8; ++m)
      acc[m] = __builtin_amdgcn_mfma_f32_16x16x32_bf16(pf, wreg[m], acc[m], 0, 0, 0);

    __syncthreads();  // single barrier: next y staged + all waves done with yB
  }

  // epilogue: pair-reduce partial accs across wc partners, then store
  f4_t* ex = (f4_t*)smem;
  const int partner = w ^ 4;
#pragma unroll
  for (int k = 0; k < 4; ++k)
    ex[w * 256 + k * 64 + lane] = acc[(1 - wc) * 4 + k];  // send partner's d-range
  __syncthreads();
#pragma unroll
  for (int k = 0; k < 4; ++k) {
    const int m = wc * 4 + k;
    f4_t other = ex[partner * 256 + k * 64 + lane];
    const int d = m * 16 + l15;
#pragma unroll
    for (int r = 0; r < 4; ++r)
      Oc1[(size_t)(i0 + I0 + q * 4 + r) * D_ + d] = acc[m][r] + other[r];
  }
}

extern "C" void kernel_launch(void* const* d_in, const int* in_sizes, int n_in,
                              void* d_out, int out_size, void* d_ws, size_t ws_size,
                              hipStream_t stream) {
  const float* x0 = (const float*)d_in[0];
  const float* x1 = (const float*)d_in[1];
  const float* W0 = (const float*)d_in[2];
  const float* W1 = (const float*)d_in[3];
  float* out = (float*)d_out;

  char* ws = (char*)d_ws;
  short* Wt = (short*)ws;                       // 512 KB, fragment-coalesced layout
  short* Xs = (short*)(ws + 524288);            // 16.78 MB, pre-swizzled bf16
  float* sq = (float*)(ws + 524288 + 16777216); // 256 KB

  prep_kernel<<<9216, 256, 0, stream>>>(x0, x1, W0, W1, Xs, sq, Wt, out);
  fused_attnconv<<<1024, NT, 0, stream>>>(Xs, sq, Wt, out);
}

// Round 7
// 93.714 us; speedup vs baseline: 2.7238x; 1.2468x over previous
//
#include <hip/hip_runtime.h>

#define B_ 32
#define L_ 1024
#define D_ 128
#define NT 512

typedef __attribute__((ext_vector_type(8))) short bf8_t;
typedef __attribute__((ext_vector_type(4))) float f4_t;

__device__ __forceinline__ unsigned cvtpk(float lo, float hi) {
  unsigned r;
  asm("v_cvt_pk_bf16_f32 %0, %1, %2" : "=v"(r) : "v"(lo), "v"(hi));
  return r;
}

__device__ __forceinline__ void gload16(const void* g, void* l) {
  __builtin_amdgcn_global_load_lds((const __attribute__((address_space(1))) void*)g,
                                   (__attribute__((address_space(3))) void*)l, 16, 0, 0);
}

// Prologue: pre-swizzled bf16 X panels + sq + channel-0 copy + W in
// fragment-coalesced layout Wc[which][j/32][d][j%32] (bf16).
__global__ __launch_bounds__(256)
void prep_kernel(const float* __restrict__ x0, const float* __restrict__ x1,
                 const float* __restrict__ W0, const float* __restrict__ W1,
                 short* __restrict__ Xs, float* __restrict__ sq,
                 short* __restrict__ Wt, float* __restrict__ out) {
  int bid = blockIdx.x;
  if (bid < 8192) {
    int t = bid * 256 + threadIdx.x;     // 0 .. 2097151
    int row_id = t >> 5;                 // (which,b,row)
    int qp = t & 31;
    int which = row_id >> 15;
    int b = (row_id >> 10) & 31;
    int row = row_id & 1023;
    const float* x = which ? x1 : x0;
    float4 v = *(const float4*)(x + ((size_t)b * L_ + row) * D_ + qp * 4);
    float* o = out + (size_t)which * (B_ * 2 * L_ * D_) + (size_t)b * (2 * L_ * D_)
             + (size_t)row * D_ + qp * 4;
    *(float4*)o = v;
    unsigned w0 = cvtpk(v.x, v.y), w1 = cvtpk(v.z, v.w);
    char* xb = (char*)Xs + (size_t)row_id * 256 + ((qp * 8) ^ ((row & 7) << 4));
    *(uint2*)xb = make_uint2(w0, w1);
    float s = v.x * v.x + v.y * v.y + v.z * v.z + v.w * v.w;
    s += __shfl_xor(s, 1); s += __shfl_xor(s, 2); s += __shfl_xor(s, 4);
    s += __shfl_xor(s, 8); s += __shfl_xor(s, 16);
    if (qp == 0) sq[row_id] = s;
  } else {
    int idx = (bid - 8192) * 256 + threadIdx.x;  // 0..262143
    int which = idx >> 17;
    int rm = idx & 131071;
    int j32 = rm >> 12;
    int d = (rm >> 5) & 127;
    int jj = rm & 31;
    const float* W = which ? W1 : W0;
    float wv = W[(j32 * 32 + jj) * D_ + d];
    Wt[idx] = (short)(cvtpk(wv, wv) & 0xffffu);
  }
}

__global__ __launch_bounds__(NT, 4)
void fused_attnconv(const short* __restrict__ Xs, const float* __restrict__ sq,
                    const short* __restrict__ Wt, float* __restrict__ out) {
  // LDS: [0,16K) y0 [16K,32K) y1 [32K,48K) w0 [48K,64K) w1 [64K,72K) P [72K,76K) sqy
  __shared__ char smem[77824];
  char* Pb = smem + 65536;
  float* sqyL = (float*)(smem + 73728);

  const int bid = blockIdx.x;
  const int x = bid & 7, g = bid >> 3;
  const int p = x + 8 * (g >> 4);       // panel id = which*32+b
  const int it = g & 15;                // i-tile (64 rows)
  const int which = p >> 5, b = p & 31;
  const int i0 = it * 64;
  const int po = (which ^ 1) * 32 + b;  // opposite tensor: y-side

  const char* apanel = (const char*)Xs + (size_t)p * (L_ * 256);
  const char* ypanel = (const char*)Xs + (size_t)po * (L_ * 256);
  const char* wbase = (const char*)Wt + (size_t)which * 262144;  // 16KB per jt
  const float* sqx_p = sq + p * L_;
  const float* sqy_p = sq + po * L_;
  float* Oc1 = out + (size_t)which * (B_ * 2 * L_ * D_) + (size_t)b * (2 * L_ * D_) + (L_ * D_);

  const int tid = threadIdx.x;
  const int lane = tid & 63;
  const int w = tid >> 6;
  const int l15 = lane & 15;
  const int q = lane >> 4;
  const int wr = w & 3;           // i-strip: rows I0..I0+15
  const int wc = w >> 2;          // j-half of the 64-wide tile: J0..J0+31
  const int I0 = wr * 16;
  const int J0 = wc * 32;
  const int swz = (l15 & 7) << 4;

  // a-fragments in registers (global Xs is pre-swizzled -> apply same XOR)
  bf8_t afr[4];
#pragma unroll
  for (int kb = 0; kb < 4; ++kb)
    afr[kb] = *(const bf8_t*)(apanel + (size_t)(i0 + I0 + l15) * 256 + ((kb * 64 + q * 16) ^ swz));
  const float sxv = sqx_p[i0 + I0 + l15];

  // stage sqy (4 KB, once)
  if (tid < 256) {
    f4_t v = *(const f4_t*)(sqy_p + tid * 4);
    *(f4_t*)(sqyL + tid * 4) = v;
  }
  // stage y-tile 0 (16 KB) + W-tile 0 (16 KB)
  gload16(ypanel + tid * 16, smem + tid * 16);
  gload16(ypanel + 8192 + tid * 16, smem + 8192 + tid * 16);
  gload16(wbase + tid * 16, smem + 32768 + tid * 16);
  gload16(wbase + 8192 + tid * 16, smem + 40960 + tid * 16);

  f4_t z4 = {0.f, 0.f, 0.f, 0.f};
  f4_t acc[8];
#pragma unroll
  for (int m = 0; m < 8; ++m) acc[m] = z4;

  __syncthreads();  // drains vmcnt(0)+lgkmcnt(0): all tiles staged

  for (int jt = 0; jt < 16; ++jt) {
    const int cur = jt & 1;
    char* yB = smem + cur * 16384;
    char* wB = smem + 32768 + cur * 16384;

    // prefetch next y+W tiles into the other buffers (lands during compute)
    if (jt < 15) {
      char* yN = smem + (1 - cur) * 16384;
      char* wN = smem + 32768 + (1 - cur) * 16384;
      const char* gy = ypanel + (jt + 1) * 16384 + tid * 16;
      const char* gw = wbase + (jt + 1) * 16384 + tid * 16;
      gload16(gy, yN + tid * 16);
      gload16(gy + 8192, yN + 8192 + tid * 16);
      gload16(gw, wN + tid * 16);
      gload16(gw + 8192, wN + 8192 + tid * 16);
    }

    // sy for this wave's j-columns (from LDS)
    f4_t sy0 = *(const f4_t*)(sqyL + jt * 64 + J0 + q * 4);
    f4_t sy1 = *(const f4_t*)(sqyL + jt * 64 + J0 + 16 + q * 4);

    // MFMA-1 (swapped): ST = y . a^T ; lane holds i=l15, j=J0+(0|16)+q*4+r
    f4_t ST0 = z4, ST1 = z4;
#pragma unroll
    for (int kb = 0; kb < 4; ++kb) {
      const int kc = (kb * 64 + q * 16) ^ swz;
      bf8_t yf0 = *(const bf8_t*)(yB + (J0 + l15) * 256 + kc);
      bf8_t yf1 = *(const bf8_t*)(yB + (J0 + 16 + l15) * 256 + kc);
      ST0 = __builtin_amdgcn_mfma_f32_16x16x32_bf16(yf0, afr[kb], ST0, 0, 0, 0);
      ST1 = __builtin_amdgcn_mfma_f32_16x16x32_bf16(yf1, afr[kb], ST1, 0, 0, 0);
    }

    // W fragments from LDS (contiguous 64B rows -> conflict-free)
    bf8_t wf[8];
#pragma unroll
    for (int m = 0; m < 8; ++m)
      wf[m] = *(const bf8_t*)(wB + wc * 8192 + (m * 16 + l15) * 64 + q * 16);

    // elementwise A = 1/(1+dist) -> wave-private P columns [J0, J0+32)
    {
      float A0 = __builtin_amdgcn_rcpf(1.0f + __builtin_amdgcn_sqrtf(fmaxf(__builtin_fmaf(-2.f, ST0[0], sxv + sy0[0]), 0.f)));
      float A1 = __builtin_amdgcn_rcpf(1.0f + __builtin_amdgcn_sqrtf(fmaxf(__builtin_fmaf(-2.f, ST0[1], sxv + sy0[1]), 0.f)));
      float A2 = __builtin_amdgcn_rcpf(1.0f + __builtin_amdgcn_sqrtf(fmaxf(__builtin_fmaf(-2.f, ST0[2], sxv + sy0[2]), 0.f)));
      float A3 = __builtin_amdgcn_rcpf(1.0f + __builtin_amdgcn_sqrtf(fmaxf(__builtin_fmaf(-2.f, ST0[3], sxv + sy0[3]), 0.f)));
      *(uint2*)(Pb + (I0 + l15) * 128 + ((J0 * 2 + q * 8) ^ swz)) =
          make_uint2(cvtpk(A0, A1), cvtpk(A2, A3));
      float B0 = __builtin_amdgcn_rcpf(1.0f + __builtin_amdgcn_sqrtf(fmaxf(__builtin_fmaf(-2.f, ST1[0], sxv + sy1[0]), 0.f)));
      float B1 = __builtin_amdgcn_rcpf(1.0f + __builtin_amdgcn_sqrtf(fmaxf(__builtin_fmaf(-2.f, ST1[1], sxv + sy1[1]), 0.f)));
      float B2 = __builtin_amdgcn_rcpf(1.0f + __builtin_amdgcn_sqrtf(fmaxf(__builtin_fmaf(-2.f, ST1[2], sxv + sy1[2]), 0.f)));
      float B3 = __builtin_amdgcn_rcpf(1.0f + __builtin_amdgcn_sqrtf(fmaxf(__builtin_fmaf(-2.f, ST1[3], sxv + sy1[3]), 0.f)));
      *(uint2*)(Pb + (I0 + l15) * 128 + ((J0 * 2 + 32 + q * 8) ^ swz)) =
          make_uint2(cvtpk(B0, B1), cvtpk(B2, B3));
    }

    // MFMA-2 (K-split): acc[m] += P[:, J0..J0+32) . W[J0..J0+32, :]
    bf8_t pf = *(const bf8_t*)(Pb + (I0 + l15) * 128 + ((J0 * 2 + q * 16) ^ swz));
#pragma unroll
    for (int m = 0; m < 8; ++m)
      acc[m] = __builtin_amdgcn_mfma_f32_16x16x32_bf16(pf, wf[m], acc[m], 0, 0, 0);

    __syncthreads();  // single barrier: next tiles staged + all waves done with cur
  }

  // epilogue: pair-reduce partial accs across wc partners, then store
  f4_t* ex = (f4_t*)smem;
  const int partner = w ^ 4;
#pragma unroll
  for (int k = 0; k < 4; ++k)
    ex[w * 256 + k * 64 + lane] = acc[(1 - wc) * 4 + k];  // send partner's d-range
  __syncthreads();
#pragma unroll
  for (int k = 0; k < 4; ++k) {
    const int m = wc * 4 + k;
    f4_t other = ex[partner * 256 + k * 64 + lane];
    const int d = m * 16 + l15;
#pragma unroll
    for (int r = 0; r < 4; ++r)
      Oc1[(size_t)(i0 + I0 + q * 4 + r) * D_ + d] = acc[m][r] + other[r];
  }
}

extern "C" void kernel_launch(void* const* d_in, const int* in_sizes, int n_in,
                              void* d_out, int out_size, void* d_ws, size_t ws_size,
                              hipStream_t stream) {
  const float* x0 = (const float*)d_in[0];
  const float* x1 = (const float*)d_in[1];
  const float* W0 = (const float*)d_in[2];
  const float* W1 = (const float*)d_in[3];
  float* out = (float*)d_out;

  char* ws = (char*)d_ws;
  short* Wt = (short*)ws;                       // 512 KB, fragment-coalesced layout
  short* Xs = (short*)(ws + 524288);            // 16.78 MB, pre-swizzled bf16
  float* sq = (float*)(ws + 524288 + 16777216); // 256 KB

  prep_kernel<<<9216, 256, 0, stream>>>(x0, x1, W0, W1, Xs, sq, Wt, out);
  fused_attnconv<<<1024, NT, 0, stream>>>(Xs, sq, Wt, out);
}

// Round 9
// 91.112 us; speedup vs baseline: 2.8016x; 1.0286x over previous
//
#include <hip/hip_runtime.h>

#define B_ 32
#define L_ 1024
#define D_ 128
#define NT 512

typedef __attribute__((ext_vector_type(8))) short bf8_t;
typedef __attribute__((ext_vector_type(4))) float f4_t;

__device__ __forceinline__ unsigned cvtpk(float lo, float hi) {
  unsigned r;
  asm("v_cvt_pk_bf16_f32 %0, %1, %2" : "=v"(r) : "v"(lo), "v"(hi));
  return r;
}

__device__ __forceinline__ void gload16(const void* g, void* l) {
  __builtin_amdgcn_global_load_lds((const __attribute__((address_space(1))) void*)g,
                                   (__attribute__((address_space(3))) void*)l, 16, 0, 0);
}

// Prologue: pre-swizzled bf16 X panels + sq + channel-0 copy + W as swizzled
// LDS-image tiles: Wt[which][t=16][d=128 rows x 128B], element (d, jj<64) at
// byte d*128 + (((jj>>3)<<4) ^ ((d&7)<<4)) + (jj&7)*2.
__global__ __launch_bounds__(256)
void prep_kernel(const float* __restrict__ x0, const float* __restrict__ x1,
                 const float* __restrict__ W0, const float* __restrict__ W1,
                 short* __restrict__ Xs, float* __restrict__ sq,
                 char* __restrict__ Wt, float* __restrict__ out) {
  int bid = blockIdx.x;
  if (bid < 8192) {
    int t = bid * 256 + threadIdx.x;     // 0 .. 2097151
    int row_id = t >> 5;                 // (which,b,row)
    int qp = t & 31;
    int which = row_id >> 15;
    int b = (row_id >> 10) & 31;
    int row = row_id & 1023;
    const float* x = which ? x1 : x0;
    float4 v = *(const float4*)(x + ((size_t)b * L_ + row) * D_ + qp * 4);
    float* o = out + (size_t)which * (B_ * 2 * L_ * D_) + (size_t)b * (2 * L_ * D_)
             + (size_t)row * D_ + qp * 4;
    *(float4*)o = v;
    unsigned w0 = cvtpk(v.x, v.y), w1 = cvtpk(v.z, v.w);
    char* xb = (char*)Xs + (size_t)row_id * 256 + ((qp * 8) ^ ((row & 7) << 4));
    *(uint2*)xb = make_uint2(w0, w1);
    float s = v.x * v.x + v.y * v.y + v.z * v.z + v.w * v.w;
    s += __shfl_xor(s, 1); s += __shfl_xor(s, 2); s += __shfl_xor(s, 4);
    s += __shfl_xor(s, 8); s += __shfl_xor(s, 16);
    if (qp == 0) sq[row_id] = s;
  } else {
    int idx = (bid - 8192) * 256 + threadIdx.x;  // 0..262143 = which*131072 + t*8192 + d*64 + jj
    int which = idx >> 17;
    int rm = idx & 131071;
    int t = rm >> 13;          // 16 tiles of 64 j
    int d = (rm >> 6) & 127;
    int jj = rm & 63;
    const float* W = which ? W1 : W0;
    float wv = W[(t * 64 + jj) * D_ + d];
    size_t byte = (size_t)which * 262144 + (size_t)t * 16384 + d * 128 +
                  ((((jj >> 3) << 4) ^ ((d & 7) << 4))) + (jj & 7) * 2;
    *(short*)(Wt + byte) = (short)(cvtpk(wv, wv) & 0xffffu);
  }
}

__global__ __launch_bounds__(NT, 4)
void fused_attnconv(const short* __restrict__ Xs, const float* __restrict__ sq,
                    const char* __restrict__ Wt, float* __restrict__ out) {
  // LDS: [0,16K) y0 [16K,32K) y1 [32K,48K) w0 [48K,64K) w1 [64K,72K) P [72K,76K) sqy
  __shared__ char smem[77824];
  char* Pb = smem + 65536;
  float* sqyL = (float*)(smem + 73728);

  const int bid = blockIdx.x;
  const int x = bid & 7, g = bid >> 3;
  const int p = x + 8 * (g >> 4);       // panel id = which*32+b
  const int it = g & 15;                // i-tile (64 rows)
  const int which = p >> 5, b = p & 31;
  const int i0 = it * 64;
  const int po = (which ^ 1) * 32 + b;  // opposite tensor: y-side

  const char* apanel = (const char*)Xs + (size_t)p * (L_ * 256);
  const char* ypanel = (const char*)Xs + (size_t)po * (L_ * 256);
  const char* wbase = Wt + (size_t)which * 262144;  // 16KB swizzled tile per jt
  const float* sqx_p = sq + p * L_;
  const float* sqy_p = sq + po * L_;
  float* Oc1 = out + (size_t)which * (B_ * 2 * L_ * D_) + (size_t)b * (2 * L_ * D_) + (L_ * D_);

  const int tid = threadIdx.x;
  const int lane = tid & 63;
  const int w = tid >> 6;
  const int l15 = lane & 15;
  const int q = lane >> 4;
  const int wr = w & 3;           // i-strip: rows I0..I0+15
  const int wc = w >> 2;          // j-half of the 64-wide tile: J0..J0+31
  const int I0 = wr * 16;
  const int J0 = wc * 32;
  const int swz = (l15 & 7) << 4;

  // a-fragments in registers (global Xs is pre-swizzled -> apply same XOR)
  bf8_t afr[4];
#pragma unroll
  for (int kb = 0; kb < 4; ++kb)
    afr[kb] = *(const bf8_t*)(apanel + (size_t)(i0 + I0 + l15) * 256 + ((kb * 64 + q * 16) ^ swz));
  const float sxv = sqx_p[i0 + I0 + l15];

  // stage sqy (4 KB, once)
  if (tid < 256) {
    f4_t v = *(const f4_t*)(sqy_p + tid * 4);
    *(f4_t*)(sqyL + tid * 4) = v;
  }
  // stage y-tile 0 (16 KB) + W-tile 0 (16 KB)
  gload16(ypanel + tid * 16, smem + tid * 16);
  gload16(ypanel + 8192 + tid * 16, smem + 8192 + tid * 16);
  gload16(wbase + tid * 16, smem + 32768 + tid * 16);
  gload16(wbase + 8192 + tid * 16, smem + 40960 + tid * 16);

  f4_t z4 = {0.f, 0.f, 0.f, 0.f};
  f4_t acc[8];
#pragma unroll
  for (int m = 0; m < 8; ++m) acc[m] = z4;

  __syncthreads();  // drains vmcnt(0)+lgkmcnt(0): all tiles staged

  for (int jt = 0; jt < 16; ++jt) {
    const int cur = jt & 1;
    char* yB = smem + cur * 16384;
    char* wB = smem + 32768 + cur * 16384;

    // prefetch next y+W tiles into the other buffers (lands during compute)
    if (jt < 15) {
      char* yN = smem + (1 - cur) * 16384;
      char* wN = smem + 32768 + (1 - cur) * 16384;
      const char* gy = ypanel + (jt + 1) * 16384 + tid * 16;
      const char* gw = wbase + (jt + 1) * 16384 + tid * 16;
      gload16(gy, yN + tid * 16);
      gload16(gy + 8192, yN + 8192 + tid * 16);
      gload16(gw, wN + tid * 16);
      gload16(gw + 8192, wN + 8192 + tid * 16);
    }

    // sy for this wave's j-columns (from LDS)
    f4_t sy0 = *(const f4_t*)(sqyL + jt * 64 + J0 + q * 4);
    f4_t sy1 = *(const f4_t*)(sqyL + jt * 64 + J0 + 16 + q * 4);

    // MFMA-1 (swapped): ST = y . a^T ; lane holds i=l15, j=J0+(0|16)+q*4+r
    f4_t ST0 = z4, ST1 = z4;
#pragma unroll
    for (int kb = 0; kb < 4; ++kb) {
      const int kc = (kb * 64 + q * 16) ^ swz;
      bf8_t yf0 = *(const bf8_t*)(yB + (J0 + l15) * 256 + kc);
      bf8_t yf1 = *(const bf8_t*)(yB + (J0 + 16 + l15) * 256 + kc);
      ST0 = __builtin_amdgcn_mfma_f32_16x16x32_bf16(yf0, afr[kb], ST0, 0, 0, 0);
      ST1 = __builtin_amdgcn_mfma_f32_16x16x32_bf16(yf1, afr[kb], ST1, 0, 0, 0);
    }

    // W fragments from LDS (swizzled rows of 128B -> 2-way banks, conflict-free)
    bf8_t wf[8];
#pragma unroll
    for (int m = 0; m < 8; ++m)
      wf[m] = *(const bf8_t*)(wB + (m * 16 + l15) * 128 + ((wc * 64 + q * 16) ^ swz));

    // elementwise A = 1/(1+dist) -> wave-private P columns [J0, J0+32)
    {
      float A0 = __builtin_amdgcn_rcpf(1.0f + __builtin_amdgcn_sqrtf(fmaxf(__builtin_fmaf(-2.f, ST0[0], sxv + sy0[0]), 0.f)));
      float A1 = __builtin_amdgcn_rcpf(1.0f + __builtin_amdgcn_sqrtf(fmaxf(__builtin_fmaf(-2.f, ST0[1], sxv + sy0[1]), 0.f)));
      float A2 = __builtin_amdgcn_rcpf(1.0f + __builtin_amdgcn_sqrtf(fmaxf(__builtin_fmaf(-2.f, ST0[2], sxv + sy0[2]), 0.f)));
      float A3 = __builtin_amdgcn_rcpf(1.0f + __builtin_amdgcn_sqrtf(fmaxf(__builtin_fmaf(-2.f, ST0[3], sxv + sy0[3]), 0.f)));
      *(uint2*)(Pb + (I0 + l15) * 128 + ((J0 * 2 + q * 8) ^ swz)) =
          make_uint2(cvtpk(A0, A1), cvtpk(A2, A3));
      float B0 = __builtin_amdgcn_rcpf(1.0f + __builtin_amdgcn_sqrtf(fmaxf(__builtin_fmaf(-2.f, ST1[0], sxv + sy1[0]), 0.f)));
      float B1 = __builtin_amdgcn_rcpf(1.0f + __builtin_amdgcn_sqrtf(fmaxf(__builtin_fmaf(-2.f, ST1[1], sxv + sy1[1]), 0.f)));
      float B2 = __builtin_amdgcn_rcpf(1.0f + __builtin_amdgcn_sqrtf(fmaxf(__builtin_fmaf(-2.f, ST1[2], sxv + sy1[2]), 0.f)));
      float B3 = __builtin_amdgcn_rcpf(1.0f + __builtin_amdgcn_sqrtf(fmaxf(__builtin_fmaf(-2.f, ST1[3], sxv + sy1[3]), 0.f)));
      *(uint2*)(Pb + (I0 + l15) * 128 + ((J0 * 2 + 32 + q * 8) ^ swz)) =
          make_uint2(cvtpk(B0, B1), cvtpk(B2, B3));
    }

    // MFMA-2 (K-split): acc[m] += P[:, J0..J0+32) . W[J0..J0+32, :]
    bf8_t pf = *(const bf8_t*)(Pb + (I0 + l15) * 128 + ((J0 * 2 + q * 16) ^ swz));
#pragma unroll
    for (int m = 0; m < 8; ++m)
      acc[m] = __builtin_amdgcn_mfma_f32_16x16x32_bf16(pf, wf[m], acc[m], 0, 0, 0);

    __syncthreads();  // single barrier: next tiles staged + all waves done with cur
  }

  // epilogue: pair-reduce partial accs across wc partners, then store
  f4_t* ex = (f4_t*)smem;
  const int partner = w ^ 4;
#pragma unroll
  for (int k = 0; k < 4; ++k)
    ex[w * 256 + k * 64 + lane] = acc[(1 - wc) * 4 + k];  // send partner's d-range
  __syncthreads();
#pragma unroll
  for (int k = 0; k < 4; ++k) {
    const int m = wc * 4 + k;
    f4_t other = ex[partner * 256 + k * 64 + lane];
    const int d = m * 16 + l15;
#pragma unroll
    for (int r = 0; r < 4; ++r)
      Oc1[(size_t)(i0 + I0 + q * 4 + r) * D_ + d] = acc[m][r] + other[r];
  }
}

extern "C" void kernel_launch(void* const* d_in, const int* in_sizes, int n_in,
                              void* d_out, int out_size, void* d_ws, size_t ws_size,
                              hipStream_t stream) {
  const float* x0 = (const float*)d_in[0];
  const float* x1 = (const float*)d_in[1];
  const float* W0 = (const float*)d_in[2];
  const float* W1 = (const float*)d_in[3];
  float* out = (float*)d_out;

  char* ws = (char*)d_ws;
  char* Wt = ws;                                // 512 KB, swizzled LDS-image tiles
  short* Xs = (short*)(ws + 524288);            // 16.78 MB, pre-swizzled bf16
  float* sq = (float*)(ws + 524288 + 16777216); // 256 KB

  prep_kernel<<<9216, 256, 0, stream>>>(x0, x1, W0, W1, Xs, sq, Wt, out);
  fused_attnconv<<<1024, NT, 0, stream>>>(Xs, sq, Wt, out);
}